// Round 23
// baseline (282.501 us; speedup 1.0000x reference)
//
#include <hip/hip_runtime.h>
#include <hip/hip_bf16.h>
#include <math.h>

#define BN 8
#define C 768
#define H 64
#define W 64
#define HW 4096
#define BOT 64
#define PD 96
#define KP 32
#define KKN 9
#define NPX (BN*HW)

typedef __hip_bfloat16 bf16;
typedef __attribute__((ext_vector_type(8))) short bf16x8;
typedef __attribute__((ext_vector_type(4))) float f32x4;
#define MFMA16(a,b,c) __builtin_amdgcn_mfma_f32_16x16x32_bf16(a,b,c,0,0,0)

__device__ __forceinline__ float gelu_f(float x) {
    return 0.5f * x * (1.0f + erff(x * 0.70710678118654752440f));
}
__device__ __forceinline__ float sigmoid_f(float x) {
    return 1.0f / (1.0f + __expf(-x));
}
__device__ __forceinline__ float bf2f(short s) {
    return __uint_as_float(((unsigned)(unsigned short)s) << 16);
}

// ---------------- prep: wdt (192) + wdsum (1) ----------------
__global__ void k_prep(const float* __restrict__ Wd, const float* __restrict__ ln_g,
                       const float* __restrict__ ln_b, const float* __restrict__ bd,
                       bf16* __restrict__ wdt, float* __restrict__ s12) {
    int bx = blockIdx.x;
    int tid = threadIdx.x;
    if (bx < 192) {
        int i = bx*256 + tid;
        if (i < C*BOT) {
            int c = i >> 6, o = i & 63;
            wdt[(size_t)o*C + c] = __float2bfloat16(ln_g[c] * Wd[(size_t)c*BOT + o]);
        }
    } else {
        __shared__ float p1[4][64], p2[4][64];
        int o = tid & 63, part = tid >> 6;
        float a1 = 0.f, a2 = 0.f;
        for (int c = part; c < C; c += 4) {
            float wv = Wd[(size_t)c*BOT + o];
            a1 += ln_g[c] * wv;
            a2 += ln_b[c] * wv;
        }
        p1[part][o] = a1; p2[part][o] = a2;
        __syncthreads();
        if (tid < 64) {
            s12[o]      = p1[0][o]+p1[1][o]+p1[2][o]+p1[3][o];
            s12[64 + o] = p2[0][o]+p2[1][o]+p2[2][o]+p2[3][o] + bd[o];
        }
    }
}

// ---------------- stage1: down 32px (0..1023) | mod (1024..1535) | offwt | dcb2 | wg1f | wut | prompt1 ----------------
// grid = 1024 + 512 + 144 + 144 + 576 + 192 + 96 = 2688
__global__ void k_stage1(const float* __restrict__ x, const bf16* __restrict__ wdt,
                         const float* __restrict__ s12, bf16* __restrict__ catb,
                         const float* __restrict__ irf, const float* __restrict__ w1,
                         const float* __restrict__ b1, const float* __restrict__ w2,
                         const float* __restrict__ b2, bf16* __restrict__ mbf,
                         const float* __restrict__ off_w, const float* __restrict__ dc_w,
                         const float* __restrict__ Wg1, const float* __restrict__ Wu,
                         const float* __restrict__ tf, const float* __restrict__ Wk,
                         const float* __restrict__ bk, const float* __restrict__ Wv,
                         const float* __restrict__ bv,
                         bf16* __restrict__ off_wt, bf16* __restrict__ dcb2,
                         bf16* __restrict__ wg1f, bf16* __restrict__ wut,
                         float* __restrict__ pk, float* __restrict__ pvout) {
    __shared__ float smem[5120];      // 20480 B shared by down/mod branches
    int tid = threadIdx.x;
    if (blockIdx.x < 1024) {
        // ---- down_fused: 32 px/block, [2][64][34] double-buffered stage ----
        int gpix = blockIdx.x * 32;
        int b = gpix >> 12;
        int hw0 = gpix & 4095;
        int w = tid >> 6, lane = tid & 63;
        int lg = lane >> 4, lm = lane & 15;
#define XT(buf,row,col) smem[(((buf)*64 + (row))*34) + (col)]
        const float* xb = x + (size_t)b*C*HW + hw0;
        int sc_ = tid >> 2;               // c-row 0..63
        int sp  = (tid & 3) << 3;         // px base 0,8,16,24
        {
            float4 v0 = *(const float4*)(xb + (size_t)sc_*HW + sp);
            float4 v1 = *(const float4*)(xb + (size_t)sc_*HW + sp + 4);
            *(float2*)&XT(0,sc_,sp)   = make_float2(v0.x, v0.y);
            *(float2*)&XT(0,sc_,sp+2) = make_float2(v0.z, v0.w);
            *(float2*)&XT(0,sc_,sp+4) = make_float2(v1.x, v1.y);
            *(float2*)&XT(0,sc_,sp+6) = make_float2(v1.z, v1.w);
        }
        __syncthreads();
        f32x4 accA = {0.f,0.f,0.f,0.f};
        f32x4 accB = {0.f,0.f,0.f,0.f};
        float ssum = 0.f, sqsum = 0.f;
        int pxg = (w >> 1) * 16;          // pixel group base (0 or 16)
        int ob  = (w & 1) * 32;           // o-block base (0 or 32)
        const bf16* arowA = wdt + (size_t)(ob + lm)*C;
        const bf16* arowB = wdt + (size_t)(ob + 16 + lm)*C;
        for (int kk = 0; kk < 12; kk++) {
            int cur = kk & 1;
            float4 n0, n1;
            if (kk < 11) {
                n0 = *(const float4*)(xb + (size_t)((kk+1)*64 + sc_)*HW + sp);
                n1 = *(const float4*)(xb + (size_t)((kk+1)*64 + sc_)*HW + sp + 4);
            }
#pragma unroll
            for (int s2 = 0; s2 < 2; s2++) {
                float xv[8];
#pragma unroll
                for (int e = 0; e < 8; e++) {
                    float v = XT(cur, s2*32 + lg*8 + e, pxg + lm);
                    xv[e] = v; ssum += v; sqsum += v*v;
                }
                union { bf16 h[8]; bf16x8 v; } ub;
#pragma unroll
                for (int e = 0; e < 8; e++) ub.h[e] = __float2bfloat16(xv[e]);
                int coff = kk*64 + s2*32 + lg*8;
                bf16x8 aA = *(const bf16x8*)(arowA + coff);
                bf16x8 aB = *(const bf16x8*)(arowB + coff);
                accA = MFMA16(aA, ub.v, accA);
                accB = MFMA16(aB, ub.v, accB);
            }
            if (kk < 11) {
                int nb = cur ^ 1;
                *(float2*)&XT(nb,sc_,sp)   = make_float2(n0.x, n0.y);
                *(float2*)&XT(nb,sc_,sp+2) = make_float2(n0.z, n0.w);
                *(float2*)&XT(nb,sc_,sp+4) = make_float2(n1.x, n1.y);
                *(float2*)&XT(nb,sc_,sp+6) = make_float2(n1.z, n1.w);
            }
            __syncthreads();
        }
        ssum  += __shfl_xor(ssum, 16);  ssum  += __shfl_xor(ssum, 32);
        sqsum += __shfl_xor(sqsum, 16); sqsum += __shfl_xor(sqsum, 32);
        float mean = ssum * (1.0f/C);
        float var  = sqsum * (1.0f/C) - mean*mean;
        float rstd = rsqrtf(var + 1e-5f);
        bf16* dst = catb + (size_t)(gpix + pxg + lm)*128;
        union { bf16 h[4]; uint2 q; } uA, uB;
#pragma unroll
        for (int r = 0; r < 4; r++) {
            int oA = ob + lg*4 + r;
            int oB = ob + 16 + lg*4 + r;
            float yA = rstd*(accA[r] - mean*s12[oA]) + s12[64 + oA];
            float yB = rstd*(accB[r] - mean*s12[oB]) + s12[64 + oB];
            uA.h[r] = __float2bfloat16(gelu_f(yA));
            uB.h[r] = __float2bfloat16(gelu_f(yB));
        }
        *(uint2*)(dst + ob + lg*4)      = uA.q;
        *(uint2*)(dst + ob + 16 + lg*4) = uB.q;
#undef XT
    } else if (blockIdx.x < 1536) {
        // ---- mod MLP + irf pack ----
        int blk = blockIdx.x - 1024;  // b*64 + hw_tile
        int b = blk >> 6; int hw0 = (blk & 63)*64;
        int px = tid & 63;
        int g = tid >> 6;
        float* tile = smem;           // [64][64]
        float* hid  = smem + 4096;    // [16][64]
        const float* ib = irf + (size_t)b*BOT*HW + hw0;
#pragma unroll
        for (int i = 0; i < 16; i++) {
            int ci = g + 4*i;
            tile[ci*64 + px] = ib[(size_t)ci*HW + px];
        }
        __syncthreads();
        {
            int xp = tid >> 2, q = tid & 3;
            union { bf16 h[16]; uint4 v[2]; } u2;
#pragma unroll
            for (int i = 0; i < 16; i++) u2.h[i] = __float2bfloat16(tile[(q*16 + i)*64 + xp]);
            uint4* d2 = (uint4*)(catb + (size_t)(b*HW + hw0 + xp)*128 + 64 + q*16);
            d2[0] = u2.v[0]; d2[1] = u2.v[1];
        }
#pragma unroll
        for (int jj = 0; jj < 4; jj++) {
            int j = g*4 + jj;
            float a = b1[j];
            for (int ci = 0; ci < 64; ci++) a += tile[ci*64 + px] * w1[j*64+ci];
            hid[j*64 + px] = gelu_f(a);
        }
        __syncthreads();
        union { bf16 h[16]; uint4 q[2]; } u;
#pragma unroll
        for (int s = 0; s < 16; s++) {
            int o = g*16 + s;
            float a = b2[o];
#pragma unroll
            for (int j = 0; j < 16; j++) a += hid[j*64 + px] * w2[o*16+j];
            u.h[s] = __float2bfloat16(sigmoid_f(a));
        }
        uint4* dst = (uint4*)(mbf + (size_t)(b*HW + hw0 + px)*64 + g*16);
        dst[0] = u.q[0]; dst[1] = u.q[1];
    } else if (blockIdx.x < 1680) {
        int i = (blockIdx.x - 1536)*256 + tid;
        if (i < 32*1152) {
            int o = i / 1152, kk = i % 1152;
            int k = kk >> 7, ci = kk & 127;
            float v = (o < 18) ? off_w[(size_t)(o*128 + ci)*9 + k] : 0.0f;
            off_wt[i] = __float2bfloat16(v);
        }
    } else if (blockIdx.x < 1824) {
        int i = (blockIdx.x - 1680)*256 + tid;
        if (i < 36864) {
            int e = i & 7;
            int lane = (i >> 3) & 63;
            int s = (i >> 9) & 1;
            int f = (i >> 10) & 3;
            int k = i >> 12;
            int lg = lane >> 4, lm = lane & 15;
            int o = f*16 + lm;
            int ci = s*32 + lg*8 + e;
            dcb2[i] = __float2bfloat16(dc_w[((size_t)o*64 + ci)*9 + k]);
        }
    } else if (blockIdx.x < 2400) {
        // ---- wg1f: lane-packed fragments [((s*2+gw)*6+f)*64+lane][8] ----
        int i = (blockIdx.x - 1824)*256 + tid;
        if (i < 192*C) {
            int e = i & 7;
            int lane = (i >> 3) & 63;
            int idx = i >> 9;          // 0..287
            int f = idx % 6;
            int sg = idx / 6;          // 0..47
            int gw = sg & 1;
            int s = sg >> 1;           // 0..23
            int lm = lane & 15, lg = lane >> 4;
            int h = gw*96 + f*16 + lm;
            int c = s*32 + lg*8 + e;
            wg1f[i] = __float2bfloat16(Wg1[(size_t)c*192 + h]);
        }
    } else if (blockIdx.x < 2592) {
        int i = (blockIdx.x - 2400)*256 + tid;
        if (i < C*BOT) {
            int c = i >> 6, k = i & 63;
            wut[i] = __float2bfloat16(Wu[(size_t)k*C + c]);
        }
    } else {
        int i = (blockIdx.x - 2592)*256 + tid;
        if (i < KP*C) {
            int k = i / C, c = i % C;
            float aK = bk[c], aV = bv[c];
            for (int p = 0; p < PD; p++) {
                float tv = tf[k*PD+p];
                aK += tv * Wk[(size_t)p*C + c];
                aV += tv * Wv[(size_t)p*C + c];
            }
            pk[i] = aK; pvout[i] = aV;
        }
    }
}

// ---------------- fused offset-conv + deformable conv [grid 512] ----------------
__global__ void k_offdef(const bf16* __restrict__ catb, const bf16* __restrict__ off_wt,
                         const float* __restrict__ off_b, const bf16* __restrict__ dcb2,
                         const bf16* __restrict__ mbf, const float* __restrict__ alpha,
                         bf16* __restrict__ xfb) {
    int blk = blockIdx.x;            // b*64 + y
    int b = blk >> 6, y = blk & 63;
    int tid = threadIdx.x;
    __shared__ char smem[49152];     // phase A: swizzled catb rows; phase B/C: offl + meta
    char* lds = smem;
    int w = tid >> 6, lane = tid & 63;
    int lg = lane >> 4, lm = lane & 15;

    // ---- phase A: offset conv (stage rows y-1..y+1, MFMA) ----
#pragma unroll
    for (int it = 0; it < 12; it++) {
        int idx = it*256 + tid;
        int ci8 = idx & 15, xx = (idx >> 4) & 63, lr = idx >> 10;
        int yy = y - 1 + lr;
        uint4 v = {0u,0u,0u,0u};
        if (yy >= 0 && yy < H)
            v = *(const uint4*)(catb + (size_t)(b*HW + yy*64 + xx)*128 + ci8*8);
        int lofs = (lr*16384 + xx*256) | ((ci8*16) ^ ((xx & 15) << 4));
        *(uint4*)(lds + lofs) = v;
    }
    __syncthreads();
    f32x4 acc0 = {0.f,0.f,0.f,0.f}, acc1 = {0.f,0.f,0.f,0.f};
    {
        const bf16* brow0 = off_wt + (size_t)lm*1152;
        const bf16* brow1 = off_wt + (size_t)(16+lm)*1152;
#pragma unroll
        for (int k = 0; k < 9; k++) {
            int ky = k/3, kx = k%3;
            int xs = w*16 + lm + kx - 1;
            bool valid = (xs >= 0 && xs < 64);
            int rowbase = ky*16384 + xs*256;
            int sw = (xs & 15) << 4;
#pragma unroll
            for (int ci0 = 0; ci0 < 128; ci0 += 32) {
                bf16x8 a = {0,0,0,0,0,0,0,0};
                if (valid) a = *(const bf16x8*)(lds + (rowbase | ((ci0*2 + lg*16) ^ sw)));
                bf16x8 bb0 = *(const bf16x8*)(brow0 + k*128 + ci0 + lg*8);
                bf16x8 bb1 = *(const bf16x8*)(brow1 + k*128 + ci0 + lg*8);
                acc0 = MFMA16(a, bb0, acc0);
                acc1 = MFMA16(a, bb1, acc1);
            }
        }
    }
    __syncthreads();                 // staging LDS now dead

    // ---- phase B: offsets -> LDS, sampling metadata ----
    float* offl = (float*)smem;                    // [18][64]
    int*   sy0  = (int*)(smem + 4608);             // [9][64]
    int*   sx0  = (int*)(smem + 6912);
    float* swy  = (float*)(smem + 9216);
    float* swx  = (float*)(smem + 11520);
    {
        float bi0 = off_b[lm];
        float bi1 = (lm < 2) ? off_b[16+lm] : 0.f;
#pragma unroll
        for (int r = 0; r < 4; r++) {
            int pr = w*16 + lg*4 + r;
            offl[lm*64 + pr] = acc0[r] + bi0;
            if (lm < 2)
                offl[(16+lm)*64 + pr] = acc1[r] + bi1;
        }
    }
    __syncthreads();
    for (int item = tid; item < 576; item += 256) {
        int k = item >> 6, xx = item & 63;
        float dy = offl[(2*k)*64 + xx];
        float dx = offl[(2*k+1)*64 + xx];
        float py  = (float)(y  - 1 + k/3) + dy;
        float pxf = (float)(xx - 1 + k%3) + dx;
        float fy = floorf(py), fx = floorf(pxf);
        sy0[k*64 + xx] = (int)fy;
        sx0[k*64 + xx] = (int)fx;
        swy[k*64 + xx] = py - fy;
        swx[k*64 + xx] = pxf - fx;
    }
    __syncthreads();

    // ---- phase C: deformable conv via MFMA + modulation ----
    int pix = w*16 + lm;
    const bf16* cb = catb + (size_t)b*HW*128;
    f32x4 acc[4];
#pragma unroll
    for (int f = 0; f < 4; f++) acc[f] = (f32x4){0.f,0.f,0.f,0.f};
#pragma unroll
    for (int k = 0; k < 9; k++) {
        int y0 = sy0[k*64 + pix], x0 = sx0[k*64 + pix];
        float wy = swy[k*64 + pix], wx = swx[k*64 + pix];
        bool vy0 = (y0 >= 0 && y0 < H), vy1 = (y0+1 >= 0 && y0+1 < H);
        bool vx0 = (x0 >= 0 && x0 < W), vx1 = (x0+1 >= 0 && x0+1 < W);
        float va[16];
#pragma unroll
        for (int i = 0; i < 16; i++) va[i] = 0.f;
#pragma unroll
        for (int cy = 0; cy < 2; cy++) {
#pragma unroll
            for (int cx = 0; cx < 2; cx++) {
                bool v = (cy ? vy1 : vy0) && (cx ? vx1 : vx0);
                if (v) {
                    float wc = (cy ? wy : (1.f-wy)) * (cx ? wx : (1.f-wx));
                    const bf16* base = cb + (size_t)((y0+cy)*64 + (x0+cx))*128;
                    bf16x8 v0 = *(const bf16x8*)(base + lg*8);
                    bf16x8 v1 = *(const bf16x8*)(base + 32 + lg*8);
#pragma unroll
                    for (int e = 0; e < 8; e++) {
                        va[e]   += wc * bf2f(v0[e]);
                        va[8+e] += wc * bf2f(v1[e]);
                    }
                }
            }
        }
        union { bf16 h[8]; bf16x8 v; } ua0, ua1;
#pragma unroll
        for (int e = 0; e < 8; e++) {
            ua0.h[e] = __float2bfloat16(va[e]);
            ua1.h[e] = __float2bfloat16(va[8+e]);
        }
        const bf16* dk = dcb2 + ((size_t)k*8*64 + lane)*8;
#pragma unroll
        for (int f = 0; f < 4; f++) {
            bf16x8 b0 = *(const bf16x8*)(dk + (size_t)(f*2+0)*64*8);
            bf16x8 b1 = *(const bf16x8*)(dk + (size_t)(f*2+1)*64*8);
            acc[f] = MFMA16(ua0.v, b0, acc[f]);
            acc[f] = MFMA16(ua1.v, b1, acc[f]);
        }
    }
    float al = alpha[0];
    const bf16* mrow = mbf + (size_t)(b*HW + y*64)*64;
    bf16* xrow = xfb + (size_t)(b*HW + y*64)*64;
    int prow = w*16 + lg*4;
#pragma unroll
    for (int f = 0; f < 4; f++) {
        int o = f*16 + lm;
#pragma unroll
        for (int r = 0; r < 4; r++) {
            int p = prow + r;
            float mm = __bfloat162float(mrow[(size_t)p*64 + o]);
            xrow[(size_t)p*64 + o] = __float2bfloat16(acc[f][r] * (1.f + al*mm));
        }
    }
}

// ---------------- stage2: up_mfma (blocks 0..2047) | promptfin (blocks 2048..2144) ----------------
__global__ void k_stage2(const float* __restrict__ x, const bf16* __restrict__ xfb,
                         const bf16* __restrict__ wut, const float* __restrict__ bu,
                         const float* __restrict__ scale, bf16* __restrict__ xres1,
                         const float* __restrict__ pk, const float* __restrict__ pv,
                         bf16* __restrict__ pkn, bf16* __restrict__ pvt) {
    __shared__ float part[32][9];
    __shared__ float rn[32];
    int tid = threadIdx.x;
    if (blockIdx.x < 2048) {
        int blk = blockIdx.x >> 2;       // b*64 + hw_tile
        int c00 = (blockIdx.x & 3) * 192;
        int b = blk >> 6; int hw0 = (blk & 63)*64;
        int w = tid >> 6, lane = tid & 63;
        int lg = lane >> 4, lm = lane & 15;
        int prow = hw0 + w*16;
        const bf16* arow = xfb + (size_t)(b*HW + prow + lm)*BOT;
        bf16x8 a0 = *(const bf16x8*)(arow + lg*8);
        bf16x8 a1 = *(const bf16x8*)(arow + 32 + lg*8);
        float sc = scale[0];
        const float* xb = x + (size_t)b*C*HW;
        bf16* xrb = xres1 + (size_t)(b*HW)*C;
#pragma unroll 3
        for (int n0 = c00; n0 < c00 + 192; n0 += 64) {
            f32x4 acc[4];
#pragma unroll
            for (int f = 0; f < 4; f++) {
                int ncol = n0 + f*16 + lm;
                bf16x8 b0 = *(const bf16x8*)(wut + (size_t)ncol*BOT + lg*8);
                bf16x8 b1 = *(const bf16x8*)(wut + (size_t)ncol*BOT + 32 + lg*8);
                f32x4 t = {0.f,0.f,0.f,0.f};
                t = MFMA16(a0, b0, t);
                t = MFMA16(a1, b1, t);
                acc[f] = t;
            }
#pragma unroll
            for (int f = 0; f < 4; f++) {
                int c = n0 + f*16 + lm;
                float bias = bu[c];
#pragma unroll
                for (int r = 0; r < 4; r++) {
                    int pix = prow + lg*4 + r;
                    float xv = xb[(size_t)c*HW + pix];
                    float rv = xv + sc*(acc[f][r] + bias);
                    xrb[(size_t)pix*C + c] = __float2bfloat16(rv);
                }
            }
        }
    } else if (blockIdx.x == 2048 + 96) {
        int t = tid;
        int k = t >> 3, sl = t & 7;
        float s = 0.f;
        for (int c = sl; c < C; c += 8) { float v = pk[(size_t)k*C+c]; s += v*v; }
        part[k][sl] = s;
        __syncthreads();
        if (t < 32) {
            float tot = 0.f;
            for (int j = 0; j < 8; j++) tot += part[t][j];
            rn[t] = 1.0f / fmaxf(sqrtf(tot), 1e-12f);
        }
        __syncthreads();
        // packed pkn: [((s*2+half)*64+lane)*8 + e]
        for (int i = t; i < KP*C; i += 256) {
            int e = i & 7;
            int lane = (i >> 3) & 63;
            int sh = i >> 9;          // 0..47
            int half = sh & 1;
            int s = sh >> 1;          // 0..23
            int lm2 = lane & 15, lg2 = lane >> 4;
            int k2 = half*16 + lm2;
            int c2 = s*32 + lg2*8 + e;
            pkn[i] = __float2bfloat16(pk[(size_t)k2*C + c2] * rn[k2]);
        }
    } else {
        int i = (blockIdx.x - 2048)*256 + tid;   // < C*KP = 24576
        int c = i >> 5, k = i & 31;
        pvt[i] = __float2bfloat16(pv[(size_t)k*C + c]);
    }
}

// ---------------- kernel 8: attn + gate, 32 px/block, packed-B fragments [grid 1024] ----------------
__global__ void k_attn_gate(const bf16* __restrict__ xres1, const bf16* __restrict__ pkn,
                            const float* __restrict__ temp,
                            const bf16* __restrict__ wg1f, const float* __restrict__ bg1,
                            const float* __restrict__ Wg2, const float* __restrict__ bg2,
                            bf16* __restrict__ atb, float* __restrict__ gbuf) {
    int pix0 = blockIdx.x * 32;
    int tid = threadIdx.x;
    int w = tid >> 6, lane = tid & 63;
    int lg = lane >> 4, lm = lane & 15;
    __shared__ char xt[32*1536];      // 48 KB: [32 rows][768 bf16], XOR-swizzled
    __shared__ float gl_part[2][32];

    {
        uint4 tmp[12];
#pragma unroll
        for (int it = 0; it < 12; it++) {
            int idx = it*256 + tid;
            int row = idx / 96, c16 = idx % 96;
            tmp[it] = *(const uint4*)(xres1 + (size_t)(pix0 + row)*C + c16*8);
        }
#pragma unroll
        for (int it = 0; it < 12; it++) {
            int idx = it*256 + tid;
            int row = idx / 96, c16 = idx % 96;
            int ofs = row*1536 + ((c16*16) ^ ((row & 7) << 4));
            *(uint4*)(xt + ofs) = tmp[it];
        }
    }
    __syncthreads();

    if (w < 2) {
        int prow = pix0 + w*16;
        int lrow = w*16 + lm;
        const char* arow = xt + lrow*1536;
        int sw = (lrow & 7) << 4;
        f32x4 acc0 = {0.f,0.f,0.f,0.f}, acc1 = {0.f,0.f,0.f,0.f};
        float ssq = 0.f;
#pragma unroll 4
        for (int c0 = 0; c0 < C; c0 += 32) {
            int s = c0 >> 5;
            bf16x8 a  = *(const bf16x8*)(arow + ((c0*2 + lg*16) ^ sw));
            bf16x8 b0 = *(const bf16x8*)(pkn + ((size_t)(s*2 + 0)*64 + lane)*8);
            bf16x8 b1 = *(const bf16x8*)(pkn + ((size_t)(s*2 + 1)*64 + lane)*8);
#pragma unroll
            for (int e = 0; e < 8; e++) {
                float av = bf2f(a[e]);
                ssq += av*av;
            }
            acc0 = MFMA16(a, b0, acc0);
            acc1 = MFMA16(a, b1, acc1);
        }
        ssq += __shfl_xor(ssq, 16);
        ssq += __shfl_xor(ssq, 32);
        float invnv = 1.0f / fmaxf(sqrtf(ssq), 1e-12f);
        float it = 1.0f / temp[0];
#pragma unroll
        for (int r = 0; r < 4; r++) {
            int pr = lg*4 + r;
            float iv = __shfl(invnv, pr);
            float s = iv * it;
            float v0 = acc0[r]*s, v1 = acc1[r]*s;
            float m = fmaxf(v0, v1);
            m = fmaxf(m, __shfl_xor(m, 1));
            m = fmaxf(m, __shfl_xor(m, 2));
            m = fmaxf(m, __shfl_xor(m, 4));
            m = fmaxf(m, __shfl_xor(m, 8));
            float e0 = __expf(v0-m), e1 = __expf(v1-m);
            float ss = e0 + e1;
            ss += __shfl_xor(ss, 1);
            ss += __shfl_xor(ss, 2);
            ss += __shfl_xor(ss, 4);
            ss += __shfl_xor(ss, 8);
            float inv = 1.0f / ss;
            bf16* ao = atb + (size_t)(prow + pr)*KP;
            ao[lm]      = __float2bfloat16(e0*inv);
            ao[16 + lm] = __float2bfloat16(e1*inv);
        }
    } else {
        int gw = w - 2;
        f32x4 acc[2][6];
#pragma unroll
        for (int pg = 0; pg < 2; pg++)
#pragma unroll
            for (int f = 0; f < 6; f++)
                acc[pg][f] = (f32x4){0.f,0.f,0.f,0.f};
        int lrow0 = lm, lrow1 = 16 + lm;
        const char* ar0 = xt + lrow0*1536;
        const char* ar1 = xt + lrow1*1536;
        int sw0 = (lrow0 & 7) << 4;
        int sw1 = (lrow1 & 7) << 4;
        for (int c0 = 0; c0 < C; c0 += 32) {
            int s = c0 >> 5;
            const bf16* bs = wg1f + ((size_t)(s*2 + gw)*6)*512 + lane*8;
            bf16x8 a[2], bb[6];
            a[0] = *(const bf16x8*)(ar0 + ((c0*2 + lg*16) ^ sw0));
            a[1] = *(const bf16x8*)(ar1 + ((c0*2 + lg*16) ^ sw1));
#pragma unroll
            for (int f = 0; f < 6; f++)
                bb[f] = *(const bf16x8*)(bs + (size_t)f*512);
#pragma unroll
            for (int pg = 0; pg < 2; pg++)
#pragma unroll
                for (int f = 0; f < 6; f++)
                    acc[pg][f] = MFMA16(a[pg], bb[f], acc[pg][f]);
        }
        float wg2v[6], bg1v[6];
#pragma unroll
        for (int f = 0; f < 6; f++) {
            int h = gw*96 + f*16 + lm;
            wg2v[f] = Wg2[h];
            bg1v[f] = bg1[h];
        }
#pragma unroll
        for (int pg = 0; pg < 2; pg++) {
#pragma unroll
            for (int r = 0; r < 4; r++) {
                float s = 0.f;
#pragma unroll
                for (int f = 0; f < 6; f++)
                    s += gelu_f(acc[pg][f][r] + bg1v[f]) * wg2v[f];
                s += __shfl_xor(s, 1);
                s += __shfl_xor(s, 2);
                s += __shfl_xor(s, 4);
                s += __shfl_xor(s, 8);
                if (lm == 0) gl_part[gw][pg*16 + lg*4 + r] = s;
            }
        }
    }
    __syncthreads();
    if (threadIdx.x < 32) {
        float t = gl_part[0][threadIdx.x] + gl_part[1][threadIdx.x];
        gbuf[pix0 + threadIdx.x] = sigmoid_f(t + bg2[0]);
    }
}

// ---------------- kernel 9: out = x + sc*(xres1 + g*(attn@pv)), LDS-staged xres1 [grid (512,4)] ----------------
__global__ void k_out(const float* __restrict__ x, const bf16* __restrict__ xres1,
                      const bf16* __restrict__ atb, const float* __restrict__ gbuf,
                      const bf16* __restrict__ pvt, const float* __restrict__ scale,
                      float* __restrict__ out) {
    int blk = blockIdx.x;
    int pix0 = blk * 64;
    int b = blk >> 6; int hw0 = (blk & 63) * 64;
    int c0 = blockIdx.y * 192;
    int tid = threadIdx.x;
    int w = tid >> 6, lane = tid & 63;
    int lg = lane >> 4, lm = lane & 15;
    __shared__ bf16 rt[64 * 200];     // 25 KB: [64 px][192 c] pitch 200
    // cooperative stage: 64 rows × 384 B contiguous = 1536 uint4, 6/thread
#pragma unroll
    for (int it = 0; it < 6; it++) {
        int idx = it*256 + tid;       // 0..1535
        int p = idx / 24;             // 24 uint4 per pixel row
        int cq = idx % 24;
        *(uint4*)(rt + p*200 + cq*8) =
            *(const uint4*)(xres1 + (size_t)(pix0 + p)*C + c0 + cq*8);
    }
    __syncthreads();
    union { bf16 h[8]; bf16x8 v; } ua;
    ua.v = *(const bf16x8*)(atb + (size_t)(pix0 + w*16 + lm)*KP + lg*8);
    float sc = scale[0];
    float gv[4];
#pragma unroll
    for (int r = 0; r < 4; r++) gv[r] = gbuf[pix0 + w*16 + lg*4 + r];
    const float* xb = x + (size_t)b*C*HW;
    float* ob = out + (size_t)b*C*HW;
    int pbase = hw0 + w*16 + lg*4;
    int plocal = w*16 + lg*4;
#pragma unroll 3
    for (int n0 = c0; n0 < c0 + 192; n0 += 64) {
#pragma unroll
        for (int f = 0; f < 4; f++) {
            int c = n0 + f*16 + lm;
            int cl = (n0 - c0) + f*16 + lm;
            bf16x8 bfrag = *(const bf16x8*)(pvt + (size_t)c*KP + lg*8);
            f32x4 z = {0.f,0.f,0.f,0.f};
            f32x4 acc = MFMA16(ua.v, bfrag, z);
            float4 x4 = *(const float4*)(xb + (size_t)c*HW + pbase);
            float4 o4;
            float xr;
            xr = bf2f(*(const short*)&rt[(plocal + 0)*200 + cl]);
            o4.x = x4.x + sc*(xr + gv[0]*acc[0]);
            xr = bf2f(*(const short*)&rt[(plocal + 1)*200 + cl]);
            o4.y = x4.y + sc*(xr + gv[1]*acc[1]);
            xr = bf2f(*(const short*)&rt[(plocal + 2)*200 + cl]);
            o4.z = x4.z + sc*(xr + gv[2]*acc[2]);
            xr = bf2f(*(const short*)&rt[(plocal + 3)*200 + cl]);
            o4.w = x4.w + sc*(xr + gv[3]*acc[3]);
            *(float4*)(ob + (size_t)c*HW + pbase) = o4;
        }
    }
}

extern "C" void kernel_launch(void* const* d_in, const int* in_sizes, int n_in,
                              void* d_out, int out_size, void* d_ws, size_t ws_size,
                              hipStream_t stream) {
    const float* x      = (const float*)d_in[0];
    const float* irf    = (const float*)d_in[1];
    const float* tf     = (const float*)d_in[2];
    const float* ln_g   = (const float*)d_in[3];
    const float* ln_b   = (const float*)d_in[4];
    const float* Wd     = (const float*)d_in[5];
    const float* bd     = (const float*)d_in[6];
    const float* Wu     = (const float*)d_in[7];
    const float* bu     = (const float*)d_in[8];
    const float* off_w  = (const float*)d_in[9];
    const float* off_b  = (const float*)d_in[10];
    const float* mod_w1 = (const float*)d_in[11];
    const float* mod_b1 = (const float*)d_in[12];
    const float* mod_w2 = (const float*)d_in[13];
    const float* mod_b2 = (const float*)d_in[14];
    const float* dc_w   = (const float*)d_in[15];
    const float* alpha  = (const float*)d_in[16];
    const float* Wk     = (const float*)d_in[17];
    const float* bk     = (const float*)d_in[18];
    const float* Wv     = (const float*)d_in[19];
    const float* bv     = (const float*)d_in[20];
    const float* temp   = (const float*)d_in[21];
    const float* Wg1    = (const float*)d_in[22];
    const float* bg1    = (const float*)d_in[23];
    const float* Wg2    = (const float*)d_in[24];
    const float* bg2    = (const float*)d_in[25];
    const float* scale  = (const float*)d_in[26];
    float* out = (float*)d_out;

    char* w = (char*)d_ws;
    auto alloc = [&](size_t bytes) {
        char* p = w;
        w += (bytes + 255) & ~(size_t)255;
        return p;
    };
    float* pk    = (float*)alloc((size_t)KP*C*4);
    float* pv    = (float*)alloc((size_t)KP*C*4);
    float* gbuf  = (float*)alloc((size_t)NPX*4);
    float* s12   = (float*)alloc((size_t)128*4);
    bf16* xres1  = (bf16*)alloc((size_t)NPX*C*2);
    bf16* pkn    = (bf16*)alloc((size_t)KP*C*2);
    bf16* pvt    = (bf16*)alloc((size_t)C*KP*2);
    bf16* atb    = (bf16*)alloc((size_t)NPX*KP*2);
    bf16* wg1f   = (bf16*)alloc((size_t)192*C*2);
    bf16* catb   = (bf16*)alloc((size_t)NPX*128*2);
    bf16* offwt  = (bf16*)alloc((size_t)32*1152*2);
    bf16* xfb    = (bf16*)alloc((size_t)NPX*BOT*2);
    bf16* wut    = (bf16*)alloc((size_t)C*BOT*2);
    bf16* mbf    = (bf16*)alloc((size_t)NPX*BOT*2);
    bf16* dcb2   = (bf16*)alloc((size_t)36864*2);
    bf16* wdt    = (bf16*)alloc((size_t)C*BOT*2);

    k_prep<<<193, 256, 0, stream>>>(Wd, ln_g, ln_b, bd, wdt, s12);
    k_stage1<<<2688, 256, 0, stream>>>(x, wdt, s12, catb,
                                       irf, mod_w1, mod_b1, mod_w2, mod_b2, mbf,
                                       off_w, dc_w, Wg1, Wu, tf, Wk, bk, Wv, bv,
                                       offwt, dcb2, wg1f, wut, pk, pv);
    k_offdef<<<512, 256, 0, stream>>>(catb, offwt, off_b, dcb2, mbf, alpha, xfb);
    k_stage2<<<2145, 256, 0, stream>>>(x, xfb, wut, bu, scale, xres1,
                                       pk, pv, pkn, pvt);
    k_attn_gate<<<1024, 256, 0, stream>>>(xres1, pkn, temp,
                                          wg1f, bg1, Wg2, bg2, atb, gbuf);
    k_out<<<dim3(512,4), 256, 0, stream>>>(x, xres1, atb, gbuf, pvt, scale, out);
}

// Round 24
// 281.545 us; speedup vs baseline: 1.0034x; 1.0034x over previous
//
#include <hip/hip_runtime.h>
#include <hip/hip_bf16.h>
#include <math.h>

#define BN 8
#define C 768
#define H 64
#define W 64
#define HW 4096
#define BOT 64
#define PD 96
#define KP 32
#define KKN 9
#define NPX (BN*HW)

typedef __hip_bfloat16 bf16;
typedef __attribute__((ext_vector_type(8))) short bf16x8;
typedef __attribute__((ext_vector_type(4))) float f32x4;
#define MFMA16(a,b,c) __builtin_amdgcn_mfma_f32_16x16x32_bf16(a,b,c,0,0,0)

__device__ __forceinline__ float gelu_f(float x) {
    return 0.5f * x * (1.0f + erff(x * 0.70710678118654752440f));
}
__device__ __forceinline__ float sigmoid_f(float x) {
    return 1.0f / (1.0f + __expf(-x));
}
__device__ __forceinline__ float bf2f(short s) {
    return __uint_as_float(((unsigned)(unsigned short)s) << 16);
}

// ---------------- prep: wdt (192) + wdsum (1) ----------------
__global__ void k_prep(const float* __restrict__ Wd, const float* __restrict__ ln_g,
                       const float* __restrict__ ln_b, const float* __restrict__ bd,
                       bf16* __restrict__ wdt, float* __restrict__ s12) {
    int bx = blockIdx.x;
    int tid = threadIdx.x;
    if (bx < 192) {
        int i = bx*256 + tid;
        if (i < C*BOT) {
            int c = i >> 6, o = i & 63;
            wdt[(size_t)o*C + c] = __float2bfloat16(ln_g[c] * Wd[(size_t)c*BOT + o]);
        }
    } else {
        __shared__ float p1[4][64], p2[4][64];
        int o = tid & 63, part = tid >> 6;
        float a1 = 0.f, a2 = 0.f;
        for (int c = part; c < C; c += 4) {
            float wv = Wd[(size_t)c*BOT + o];
            a1 += ln_g[c] * wv;
            a2 += ln_b[c] * wv;
        }
        p1[part][o] = a1; p2[part][o] = a2;
        __syncthreads();
        if (tid < 64) {
            s12[o]      = p1[0][o]+p1[1][o]+p1[2][o]+p1[3][o];
            s12[64 + o] = p2[0][o]+p2[1][o]+p2[2][o]+p2[3][o] + bd[o];
        }
    }
}

// ---------------- stage1: down 32px (0..1023) | mod (1024..1535) | offwt | dcb2 | wg1f | wut | prompt1 ----------------
// grid = 1024 + 512 + 144 + 144 + 576 + 192 + 96 = 2688
__global__ void k_stage1(const float* __restrict__ x, const bf16* __restrict__ wdt,
                         const float* __restrict__ s12, bf16* __restrict__ catb,
                         const float* __restrict__ irf, const float* __restrict__ w1,
                         const float* __restrict__ b1, const float* __restrict__ w2,
                         const float* __restrict__ b2, bf16* __restrict__ mbf,
                         const float* __restrict__ off_w, const float* __restrict__ dc_w,
                         const float* __restrict__ Wg1, const float* __restrict__ Wu,
                         const float* __restrict__ tf, const float* __restrict__ Wk,
                         const float* __restrict__ bk, const float* __restrict__ Wv,
                         const float* __restrict__ bv,
                         bf16* __restrict__ off_wt, bf16* __restrict__ dcb2,
                         bf16* __restrict__ wg1f, bf16* __restrict__ wut,
                         float* __restrict__ pk, float* __restrict__ pvout) {
    __shared__ float smem[5120];      // 20480 B shared by down/mod branches
    int tid = threadIdx.x;
    if (blockIdx.x < 1024) {
        // ---- down_fused: 32 px/block, [2][64][34] double-buffered stage ----
        int gpix = blockIdx.x * 32;
        int b = gpix >> 12;
        int hw0 = gpix & 4095;
        int w = tid >> 6, lane = tid & 63;
        int lg = lane >> 4, lm = lane & 15;
#define XT(buf,row,col) smem[(((buf)*64 + (row))*34) + (col)]
        const float* xb = x + (size_t)b*C*HW + hw0;
        int sc_ = tid >> 2;               // c-row 0..63
        int sp  = (tid & 3) << 3;         // px base 0,8,16,24
        {
            float4 v0 = *(const float4*)(xb + (size_t)sc_*HW + sp);
            float4 v1 = *(const float4*)(xb + (size_t)sc_*HW + sp + 4);
            *(float2*)&XT(0,sc_,sp)   = make_float2(v0.x, v0.y);
            *(float2*)&XT(0,sc_,sp+2) = make_float2(v0.z, v0.w);
            *(float2*)&XT(0,sc_,sp+4) = make_float2(v1.x, v1.y);
            *(float2*)&XT(0,sc_,sp+6) = make_float2(v1.z, v1.w);
        }
        __syncthreads();
        f32x4 accA = {0.f,0.f,0.f,0.f};
        f32x4 accB = {0.f,0.f,0.f,0.f};
        float ssum = 0.f, sqsum = 0.f;
        int pxg = (w >> 1) * 16;          // pixel group base (0 or 16)
        int ob  = (w & 1) * 32;           // o-block base (0 or 32)
        const bf16* arowA = wdt + (size_t)(ob + lm)*C;
        const bf16* arowB = wdt + (size_t)(ob + 16 + lm)*C;
        for (int kk = 0; kk < 12; kk++) {
            int cur = kk & 1;
            float4 n0, n1;
            if (kk < 11) {
                n0 = *(const float4*)(xb + (size_t)((kk+1)*64 + sc_)*HW + sp);
                n1 = *(const float4*)(xb + (size_t)((kk+1)*64 + sc_)*HW + sp + 4);
            }
#pragma unroll
            for (int s2 = 0; s2 < 2; s2++) {
                float xv[8];
#pragma unroll
                for (int e = 0; e < 8; e++) {
                    float v = XT(cur, s2*32 + lg*8 + e, pxg + lm);
                    xv[e] = v; ssum += v; sqsum += v*v;
                }
                union { bf16 h[8]; bf16x8 v; } ub;
#pragma unroll
                for (int e = 0; e < 8; e++) ub.h[e] = __float2bfloat16(xv[e]);
                int coff = kk*64 + s2*32 + lg*8;
                bf16x8 aA = *(const bf16x8*)(arowA + coff);
                bf16x8 aB = *(const bf16x8*)(arowB + coff);
                accA = MFMA16(aA, ub.v, accA);
                accB = MFMA16(aB, ub.v, accB);
            }
            if (kk < 11) {
                int nb = cur ^ 1;
                *(float2*)&XT(nb,sc_,sp)   = make_float2(n0.x, n0.y);
                *(float2*)&XT(nb,sc_,sp+2) = make_float2(n0.z, n0.w);
                *(float2*)&XT(nb,sc_,sp+4) = make_float2(n1.x, n1.y);
                *(float2*)&XT(nb,sc_,sp+6) = make_float2(n1.z, n1.w);
            }
            __syncthreads();
        }
        ssum  += __shfl_xor(ssum, 16);  ssum  += __shfl_xor(ssum, 32);
        sqsum += __shfl_xor(sqsum, 16); sqsum += __shfl_xor(sqsum, 32);
        float mean = ssum * (1.0f/C);
        float var  = sqsum * (1.0f/C) - mean*mean;
        float rstd = rsqrtf(var + 1e-5f);
        bf16* dst = catb + (size_t)(gpix + pxg + lm)*128;
        union { bf16 h[4]; uint2 q; } uA, uB;
#pragma unroll
        for (int r = 0; r < 4; r++) {
            int oA = ob + lg*4 + r;
            int oB = ob + 16 + lg*4 + r;
            float yA = rstd*(accA[r] - mean*s12[oA]) + s12[64 + oA];
            float yB = rstd*(accB[r] - mean*s12[oB]) + s12[64 + oB];
            uA.h[r] = __float2bfloat16(gelu_f(yA));
            uB.h[r] = __float2bfloat16(gelu_f(yB));
        }
        *(uint2*)(dst + ob + lg*4)      = uA.q;
        *(uint2*)(dst + ob + 16 + lg*4) = uB.q;
#undef XT
    } else if (blockIdx.x < 1536) {
        // ---- mod MLP + irf pack ----
        int blk = blockIdx.x - 1024;  // b*64 + hw_tile
        int b = blk >> 6; int hw0 = (blk & 63)*64;
        int px = tid & 63;
        int g = tid >> 6;
        float* tile = smem;           // [64][64]
        float* hid  = smem + 4096;    // [16][64]
        const float* ib = irf + (size_t)b*BOT*HW + hw0;
#pragma unroll
        for (int i = 0; i < 16; i++) {
            int ci = g + 4*i;
            tile[ci*64 + px] = ib[(size_t)ci*HW + px];
        }
        __syncthreads();
        {
            int xp = tid >> 2, q = tid & 3;
            union { bf16 h[16]; uint4 v[2]; } u2;
#pragma unroll
            for (int i = 0; i < 16; i++) u2.h[i] = __float2bfloat16(tile[(q*16 + i)*64 + xp]);
            uint4* d2 = (uint4*)(catb + (size_t)(b*HW + hw0 + xp)*128 + 64 + q*16);
            d2[0] = u2.v[0]; d2[1] = u2.v[1];
        }
#pragma unroll
        for (int jj = 0; jj < 4; jj++) {
            int j = g*4 + jj;
            float a = b1[j];
            for (int ci = 0; ci < 64; ci++) a += tile[ci*64 + px] * w1[j*64+ci];
            hid[j*64 + px] = gelu_f(a);
        }
        __syncthreads();
        union { bf16 h[16]; uint4 q[2]; } u;
#pragma unroll
        for (int s = 0; s < 16; s++) {
            int o = g*16 + s;
            float a = b2[o];
#pragma unroll
            for (int j = 0; j < 16; j++) a += hid[j*64 + px] * w2[o*16+j];
            u.h[s] = __float2bfloat16(sigmoid_f(a));
        }
        uint4* dst = (uint4*)(mbf + (size_t)(b*HW + hw0 + px)*64 + g*16);
        dst[0] = u.q[0]; dst[1] = u.q[1];
    } else if (blockIdx.x < 1680) {
        int i = (blockIdx.x - 1536)*256 + tid;
        if (i < 32*1152) {
            int o = i / 1152, kk = i % 1152;
            int k = kk >> 7, ci = kk & 127;
            float v = (o < 18) ? off_w[(size_t)(o*128 + ci)*9 + k] : 0.0f;
            off_wt[i] = __float2bfloat16(v);
        }
    } else if (blockIdx.x < 1824) {
        int i = (blockIdx.x - 1680)*256 + tid;
        if (i < 36864) {
            int e = i & 7;
            int lane = (i >> 3) & 63;
            int s = (i >> 9) & 1;
            int f = (i >> 10) & 3;
            int k = i >> 12;
            int lg = lane >> 4, lm = lane & 15;
            int o = f*16 + lm;
            int ci = s*32 + lg*8 + e;
            dcb2[i] = __float2bfloat16(dc_w[((size_t)o*64 + ci)*9 + k]);
        }
    } else if (blockIdx.x < 2400) {
        // ---- wg1f: lane-packed fragments [((s*2+gw)*6+f)*64+lane][8] ----
        int i = (blockIdx.x - 1824)*256 + tid;
        if (i < 192*C) {
            int e = i & 7;
            int lane = (i >> 3) & 63;
            int idx = i >> 9;          // 0..287
            int f = idx % 6;
            int sg = idx / 6;          // 0..47
            int gw = sg & 1;
            int s = sg >> 1;           // 0..23
            int lm = lane & 15, lg = lane >> 4;
            int h = gw*96 + f*16 + lm;
            int c = s*32 + lg*8 + e;
            wg1f[i] = __float2bfloat16(Wg1[(size_t)c*192 + h]);
        }
    } else if (blockIdx.x < 2592) {
        int i = (blockIdx.x - 2400)*256 + tid;
        if (i < C*BOT) {
            int c = i >> 6, k = i & 63;
            wut[i] = __float2bfloat16(Wu[(size_t)k*C + c]);
        }
    } else {
        int i = (blockIdx.x - 2592)*256 + tid;
        if (i < KP*C) {
            int k = i / C, c = i % C;
            float aK = bk[c], aV = bv[c];
            for (int p = 0; p < PD; p++) {
                float tv = tf[k*PD+p];
                aK += tv * Wk[(size_t)p*C + c];
                aV += tv * Wv[(size_t)p*C + c];
            }
            pk[i] = aK; pvout[i] = aV;
        }
    }
}

// ---------------- fused offset-conv + deformable conv [grid 512] ----------------
__global__ void k_offdef(const bf16* __restrict__ catb, const bf16* __restrict__ off_wt,
                         const float* __restrict__ off_b, const bf16* __restrict__ dcb2,
                         const bf16* __restrict__ mbf, const float* __restrict__ alpha,
                         bf16* __restrict__ xfb) {
    int blk = blockIdx.x;            // b*64 + y
    int b = blk >> 6, y = blk & 63;
    int tid = threadIdx.x;
    __shared__ char smem[49152];     // phase A: swizzled catb rows; phase B/C: offl + meta
    char* lds = smem;
    int w = tid >> 6, lane = tid & 63;
    int lg = lane >> 4, lm = lane & 15;

    // ---- phase A: offset conv (stage rows y-1..y+1, MFMA) ----
#pragma unroll
    for (int it = 0; it < 12; it++) {
        int idx = it*256 + tid;
        int ci8 = idx & 15, xx = (idx >> 4) & 63, lr = idx >> 10;
        int yy = y - 1 + lr;
        uint4 v = {0u,0u,0u,0u};
        if (yy >= 0 && yy < H)
            v = *(const uint4*)(catb + (size_t)(b*HW + yy*64 + xx)*128 + ci8*8);
        int lofs = (lr*16384 + xx*256) | ((ci8*16) ^ ((xx & 15) << 4));
        *(uint4*)(lds + lofs) = v;
    }
    __syncthreads();
    f32x4 acc0 = {0.f,0.f,0.f,0.f}, acc1 = {0.f,0.f,0.f,0.f};
    {
        const bf16* brow0 = off_wt + (size_t)lm*1152;
        const bf16* brow1 = off_wt + (size_t)(16+lm)*1152;
#pragma unroll
        for (int k = 0; k < 9; k++) {
            int ky = k/3, kx = k%3;
            int xs = w*16 + lm + kx - 1;
            bool valid = (xs >= 0 && xs < 64);
            int rowbase = ky*16384 + xs*256;
            int sw = (xs & 15) << 4;
#pragma unroll
            for (int ci0 = 0; ci0 < 128; ci0 += 32) {
                bf16x8 a = {0,0,0,0,0,0,0,0};
                if (valid) a = *(const bf16x8*)(lds + (rowbase | ((ci0*2 + lg*16) ^ sw)));
                bf16x8 bb0 = *(const bf16x8*)(brow0 + k*128 + ci0 + lg*8);
                bf16x8 bb1 = *(const bf16x8*)(brow1 + k*128 + ci0 + lg*8);
                acc0 = MFMA16(a, bb0, acc0);
                acc1 = MFMA16(a, bb1, acc1);
            }
        }
    }
    __syncthreads();                 // staging LDS now dead

    // ---- phase B: offsets -> LDS, sampling metadata ----
    float* offl = (float*)smem;                    // [18][64]
    int*   sy0  = (int*)(smem + 4608);             // [9][64]
    int*   sx0  = (int*)(smem + 6912);
    float* swy  = (float*)(smem + 9216);
    float* swx  = (float*)(smem + 11520);
    {
        float bi0 = off_b[lm];
        float bi1 = (lm < 2) ? off_b[16+lm] : 0.f;
#pragma unroll
        for (int r = 0; r < 4; r++) {
            int pr = w*16 + lg*4 + r;
            offl[lm*64 + pr] = acc0[r] + bi0;
            if (lm < 2)
                offl[(16+lm)*64 + pr] = acc1[r] + bi1;
        }
    }
    __syncthreads();
    for (int item = tid; item < 576; item += 256) {
        int k = item >> 6, xx = item & 63;
        float dy = offl[(2*k)*64 + xx];
        float dx = offl[(2*k+1)*64 + xx];
        float py  = (float)(y  - 1 + k/3) + dy;
        float pxf = (float)(xx - 1 + k%3) + dx;
        float fy = floorf(py), fx = floorf(pxf);
        sy0[k*64 + xx] = (int)fy;
        sx0[k*64 + xx] = (int)fx;
        swy[k*64 + xx] = py - fy;
        swx[k*64 + xx] = pxf - fx;
    }
    __syncthreads();

    // ---- phase C: deformable conv via MFMA + modulation ----
    int pix = w*16 + lm;
    const bf16* cb = catb + (size_t)b*HW*128;
    f32x4 acc[4];
#pragma unroll
    for (int f = 0; f < 4; f++) acc[f] = (f32x4){0.f,0.f,0.f,0.f};
#pragma unroll
    for (int k = 0; k < 9; k++) {
        int y0 = sy0[k*64 + pix], x0 = sx0[k*64 + pix];
        float wy = swy[k*64 + pix], wx = swx[k*64 + pix];
        bool vy0 = (y0 >= 0 && y0 < H), vy1 = (y0+1 >= 0 && y0+1 < H);
        bool vx0 = (x0 >= 0 && x0 < W), vx1 = (x0+1 >= 0 && x0+1 < W);
        float va[16];
#pragma unroll
        for (int i = 0; i < 16; i++) va[i] = 0.f;
#pragma unroll
        for (int cy = 0; cy < 2; cy++) {
#pragma unroll
            for (int cx = 0; cx < 2; cx++) {
                bool v = (cy ? vy1 : vy0) && (cx ? vx1 : vx0);
                if (v) {
                    float wc = (cy ? wy : (1.f-wy)) * (cx ? wx : (1.f-wx));
                    const bf16* base = cb + (size_t)((y0+cy)*64 + (x0+cx))*128;
                    bf16x8 v0 = *(const bf16x8*)(base + lg*8);
                    bf16x8 v1 = *(const bf16x8*)(base + 32 + lg*8);
#pragma unroll
                    for (int e = 0; e < 8; e++) {
                        va[e]   += wc * bf2f(v0[e]);
                        va[8+e] += wc * bf2f(v1[e]);
                    }
                }
            }
        }
        union { bf16 h[8]; bf16x8 v; } ua0, ua1;
#pragma unroll
        for (int e = 0; e < 8; e++) {
            ua0.h[e] = __float2bfloat16(va[e]);
            ua1.h[e] = __float2bfloat16(va[8+e]);
        }
        const bf16* dk = dcb2 + ((size_t)k*8*64 + lane)*8;
#pragma unroll
        for (int f = 0; f < 4; f++) {
            bf16x8 b0 = *(const bf16x8*)(dk + (size_t)(f*2+0)*64*8);
            bf16x8 b1 = *(const bf16x8*)(dk + (size_t)(f*2+1)*64*8);
            acc[f] = MFMA16(ua0.v, b0, acc[f]);
            acc[f] = MFMA16(ua1.v, b1, acc[f]);
        }
    }
    float al = alpha[0];
    const bf16* mrow = mbf + (size_t)(b*HW + y*64)*64;
    bf16* xrow = xfb + (size_t)(b*HW + y*64)*64;
    int prow = w*16 + lg*4;
#pragma unroll
    for (int f = 0; f < 4; f++) {
        int o = f*16 + lm;
#pragma unroll
        for (int r = 0; r < 4; r++) {
            int p = prow + r;
            float mm = __bfloat162float(mrow[(size_t)p*64 + o]);
            xrow[(size_t)p*64 + o] = __float2bfloat16(acc[f][r] * (1.f + al*mm));
        }
    }
}

// ---------------- stage2: up_mfma + LDS-vectored writes (0..2047) | promptfin (2048..2144) ----------------
__global__ void k_stage2(const float* __restrict__ x, const bf16* __restrict__ xfb,
                         const bf16* __restrict__ wut, const float* __restrict__ bu,
                         const float* __restrict__ scale, bf16* __restrict__ xres1,
                         const float* __restrict__ pk, const float* __restrict__ pv,
                         bf16* __restrict__ pkn, bf16* __restrict__ pvt) {
    __shared__ char s2mem[64*216*2];  // 27648 B; up: bf16 tile [64][216]; promptfin: part/rn
    int tid = threadIdx.x;
    if (blockIdx.x < 2048) {
        bf16* rt = (bf16*)s2mem;      // [64 px][192 c] pitch 216
        int blk = blockIdx.x >> 2;       // b*64 + hw_tile
        int c00 = (blockIdx.x & 3) * 192;
        int b = blk >> 6; int hw0 = (blk & 63)*64;
        int w = tid >> 6, lane = tid & 63;
        int lg = lane >> 4, lm = lane & 15;
        int prow = hw0 + w*16;
        const bf16* arow = xfb + (size_t)(b*HW + prow + lm)*BOT;
        bf16x8 a0 = *(const bf16x8*)(arow + lg*8);
        bf16x8 a1 = *(const bf16x8*)(arow + 32 + lg*8);
        float sc = scale[0];
        const float* xb = x + (size_t)b*C*HW;
        int plocal = w*16 + lg*4;
#pragma unroll 3
        for (int n0 = c00; n0 < c00 + 192; n0 += 64) {
            f32x4 acc[4];
#pragma unroll
            for (int f = 0; f < 4; f++) {
                int ncol = n0 + f*16 + lm;
                bf16x8 b0 = *(const bf16x8*)(wut + (size_t)ncol*BOT + lg*8);
                bf16x8 b1 = *(const bf16x8*)(wut + (size_t)ncol*BOT + 32 + lg*8);
                f32x4 t = {0.f,0.f,0.f,0.f};
                t = MFMA16(a0, b0, t);
                t = MFMA16(a1, b1, t);
                acc[f] = t;
            }
#pragma unroll
            for (int f = 0; f < 4; f++) {
                int c = n0 + f*16 + lm;
                float bias = bu[c];
                float4 x4 = *(const float4*)(xb + (size_t)c*HW + prow + lg*4);
                int cl = (n0 - c00) + f*16 + lm;
                rt[(plocal + 0)*216 + cl] = __float2bfloat16(x4.x + sc*(acc[f][0] + bias));
                rt[(plocal + 1)*216 + cl] = __float2bfloat16(x4.y + sc*(acc[f][1] + bias));
                rt[(plocal + 2)*216 + cl] = __float2bfloat16(x4.z + sc*(acc[f][2] + bias));
                rt[(plocal + 3)*216 + cl] = __float2bfloat16(x4.w + sc*(acc[f][3] + bias));
            }
        }
        __syncthreads();
        // cooperative vectored write: 64 rows × 192 c = 1536 uint4, 6/thread
        bf16* xrb = xres1 + (size_t)(b*HW + hw0)*C + c00;
#pragma unroll
        for (int it = 0; it < 6; it++) {
            int idx = it*256 + tid;
            int p = idx / 24, cq = idx % 24;
            *(uint4*)(xrb + (size_t)p*C + cq*8) = *(const uint4*)(rt + p*216 + cq*8);
        }
    } else if (blockIdx.x == 2048 + 96) {
        float (*part)[9] = (float(*)[9])s2mem;
        float* rn = (float*)(s2mem + 32*9*4);
        int t = tid;
        int k = t >> 3, sl = t & 7;
        float s = 0.f;
        for (int c = sl; c < C; c += 8) { float v = pk[(size_t)k*C+c]; s += v*v; }
        part[k][sl] = s;
        __syncthreads();
        if (t < 32) {
            float tot = 0.f;
            for (int j = 0; j < 8; j++) tot += part[t][j];
            rn[t] = 1.0f / fmaxf(sqrtf(tot), 1e-12f);
        }
        __syncthreads();
        // packed pkn: [((s*2+half)*64+lane)*8 + e]
        for (int i = t; i < KP*C; i += 256) {
            int e = i & 7;
            int lane = (i >> 3) & 63;
            int sh = i >> 9;          // 0..47
            int half = sh & 1;
            int s = sh >> 1;          // 0..23
            int lm2 = lane & 15, lg2 = lane >> 4;
            int k2 = half*16 + lm2;
            int c2 = s*32 + lg2*8 + e;
            pkn[i] = __float2bfloat16(pk[(size_t)k2*C + c2] * rn[k2]);
        }
    } else {
        int i = (blockIdx.x - 2048)*256 + tid;   // < C*KP = 24576
        int c = i >> 5, k = i & 31;
        pvt[i] = __float2bfloat16(pv[(size_t)k*C + c]);
    }
}

// ---------------- kernel 8: attn + gate, 32 px/block, packed-B fragments [grid 1024] ----------------
__global__ void k_attn_gate(const bf16* __restrict__ xres1, const bf16* __restrict__ pkn,
                            const float* __restrict__ temp,
                            const bf16* __restrict__ wg1f, const float* __restrict__ bg1,
                            const float* __restrict__ Wg2, const float* __restrict__ bg2,
                            bf16* __restrict__ atb, float* __restrict__ gbuf) {
    int pix0 = blockIdx.x * 32;
    int tid = threadIdx.x;
    int w = tid >> 6, lane = tid & 63;
    int lg = lane >> 4, lm = lane & 15;
    __shared__ char xt[32*1536];      // 48 KB: [32 rows][768 bf16], XOR-swizzled
    __shared__ float gl_part[2][32];

    {
        uint4 tmp[12];
#pragma unroll
        for (int it = 0; it < 12; it++) {
            int idx = it*256 + tid;
            int row = idx / 96, c16 = idx % 96;
            tmp[it] = *(const uint4*)(xres1 + (size_t)(pix0 + row)*C + c16*8);
        }
#pragma unroll
        for (int it = 0; it < 12; it++) {
            int idx = it*256 + tid;
            int row = idx / 96, c16 = idx % 96;
            int ofs = row*1536 + ((c16*16) ^ ((row & 7) << 4));
            *(uint4*)(xt + ofs) = tmp[it];
        }
    }
    __syncthreads();

    if (w < 2) {
        int prow = pix0 + w*16;
        int lrow = w*16 + lm;
        const char* arow = xt + lrow*1536;
        int sw = (lrow & 7) << 4;
        f32x4 acc0 = {0.f,0.f,0.f,0.f}, acc1 = {0.f,0.f,0.f,0.f};
        float ssq = 0.f;
#pragma unroll 4
        for (int c0 = 0; c0 < C; c0 += 32) {
            int s = c0 >> 5;
            bf16x8 a  = *(const bf16x8*)(arow + ((c0*2 + lg*16) ^ sw));
            bf16x8 b0 = *(const bf16x8*)(pkn + ((size_t)(s*2 + 0)*64 + lane)*8);
            bf16x8 b1 = *(const bf16x8*)(pkn + ((size_t)(s*2 + 1)*64 + lane)*8);
#pragma unroll
            for (int e = 0; e < 8; e++) {
                float av = bf2f(a[e]);
                ssq += av*av;
            }
            acc0 = MFMA16(a, b0, acc0);
            acc1 = MFMA16(a, b1, acc1);
        }
        ssq += __shfl_xor(ssq, 16);
        ssq += __shfl_xor(ssq, 32);
        float invnv = 1.0f / fmaxf(sqrtf(ssq), 1e-12f);
        float it = 1.0f / temp[0];
#pragma unroll
        for (int r = 0; r < 4; r++) {
            int pr = lg*4 + r;
            float iv = __shfl(invnv, pr);
            float s = iv * it;
            float v0 = acc0[r]*s, v1 = acc1[r]*s;
            float m = fmaxf(v0, v1);
            m = fmaxf(m, __shfl_xor(m, 1));
            m = fmaxf(m, __shfl_xor(m, 2));
            m = fmaxf(m, __shfl_xor(m, 4));
            m = fmaxf(m, __shfl_xor(m, 8));
            float e0 = __expf(v0-m), e1 = __expf(v1-m);
            float ss = e0 + e1;
            ss += __shfl_xor(ss, 1);
            ss += __shfl_xor(ss, 2);
            ss += __shfl_xor(ss, 4);
            ss += __shfl_xor(ss, 8);
            float inv = 1.0f / ss;
            bf16* ao = atb + (size_t)(prow + pr)*KP;
            ao[lm]      = __float2bfloat16(e0*inv);
            ao[16 + lm] = __float2bfloat16(e1*inv);
        }
    } else {
        int gw = w - 2;
        f32x4 acc[2][6];
#pragma unroll
        for (int pg = 0; pg < 2; pg++)
#pragma unroll
            for (int f = 0; f < 6; f++)
                acc[pg][f] = (f32x4){0.f,0.f,0.f,0.f};
        int lrow0 = lm, lrow1 = 16 + lm;
        const char* ar0 = xt + lrow0*1536;
        const char* ar1 = xt + lrow1*1536;
        int sw0 = (lrow0 & 7) << 4;
        int sw1 = (lrow1 & 7) << 4;
        for (int c0 = 0; c0 < C; c0 += 32) {
            int s = c0 >> 5;
            const bf16* bs = wg1f + ((size_t)(s*2 + gw)*6)*512 + lane*8;
            bf16x8 a[2], bb[6];
            a[0] = *(const bf16x8*)(ar0 + ((c0*2 + lg*16) ^ sw0));
            a[1] = *(const bf16x8*)(ar1 + ((c0*2 + lg*16) ^ sw1));
#pragma unroll
            for (int f = 0; f < 6; f++)
                bb[f] = *(const bf16x8*)(bs + (size_t)f*512);
#pragma unroll
            for (int pg = 0; pg < 2; pg++)
#pragma unroll
                for (int f = 0; f < 6; f++)
                    acc[pg][f] = MFMA16(a[pg], bb[f], acc[pg][f]);
        }
        float wg2v[6], bg1v[6];
#pragma unroll
        for (int f = 0; f < 6; f++) {
            int h = gw*96 + f*16 + lm;
            wg2v[f] = Wg2[h];
            bg1v[f] = bg1[h];
        }
#pragma unroll
        for (int pg = 0; pg < 2; pg++) {
#pragma unroll
            for (int r = 0; r < 4; r++) {
                float s = 0.f;
#pragma unroll
                for (int f = 0; f < 6; f++)
                    s += gelu_f(acc[pg][f][r] + bg1v[f]) * wg2v[f];
                s += __shfl_xor(s, 1);
                s += __shfl_xor(s, 2);
                s += __shfl_xor(s, 4);
                s += __shfl_xor(s, 8);
                if (lm == 0) gl_part[gw][pg*16 + lg*4 + r] = s;
            }
        }
    }
    __syncthreads();
    if (threadIdx.x < 32) {
        float t = gl_part[0][threadIdx.x] + gl_part[1][threadIdx.x];
        gbuf[pix0 + threadIdx.x] = sigmoid_f(t + bg2[0]);
    }
}

// ---------------- kernel 9: out = x + sc*(xres1 + g*(attn@pv)), LDS-staged xres1 [grid (512,4)] ----------------
__global__ void k_out(const float* __restrict__ x, const bf16* __restrict__ xres1,
                      const bf16* __restrict__ atb, const float* __restrict__ gbuf,
                      const bf16* __restrict__ pvt, const float* __restrict__ scale,
                      float* __restrict__ out) {
    int blk = blockIdx.x;
    int pix0 = blk * 64;
    int b = blk >> 6; int hw0 = (blk & 63) * 64;
    int c0 = blockIdx.y * 192;
    int tid = threadIdx.x;
    int w = tid >> 6, lane = tid & 63;
    int lg = lane >> 4, lm = lane & 15;
    __shared__ bf16 rt[64 * 200];     // 25 KB: [64 px][192 c] pitch 200
#pragma unroll
    for (int it = 0; it < 6; it++) {
        int idx = it*256 + tid;       // 0..1535
        int p = idx / 24;             // 24 uint4 per pixel row
        int cq = idx % 24;
        *(uint4*)(rt + p*200 + cq*8) =
            *(const uint4*)(xres1 + (size_t)(pix0 + p)*C + c0 + cq*8);
    }
    __syncthreads();
    union { bf16 h[8]; bf16x8 v; } ua;
    ua.v = *(const bf16x8*)(atb + (size_t)(pix0 + w*16 + lm)*KP + lg*8);
    float sc = scale[0];
    float gv[4];
#pragma unroll
    for (int r = 0; r < 4; r++) gv[r] = gbuf[pix0 + w*16 + lg*4 + r];
    const float* xb = x + (size_t)b*C*HW;
    float* ob = out + (size_t)b*C*HW;
    int pbase = hw0 + w*16 + lg*4;
    int plocal = w*16 + lg*4;
#pragma unroll 3
    for (int n0 = c0; n0 < c0 + 192; n0 += 64) {
#pragma unroll
        for (int f = 0; f < 4; f++) {
            int c = n0 + f*16 + lm;
            int cl = (n0 - c0) + f*16 + lm;
            bf16x8 bfrag = *(const bf16x8*)(pvt + (size_t)c*KP + lg*8);
            f32x4 z = {0.f,0.f,0.f,0.f};
            f32x4 acc = MFMA16(ua.v, bfrag, z);
            float4 x4 = *(const float4*)(xb + (size_t)c*HW + pbase);
            float4 o4;
            float xr;
            xr = bf2f(*(const short*)&rt[(plocal + 0)*200 + cl]);
            o4.x = x4.x + sc*(xr + gv[0]*acc[0]);
            xr = bf2f(*(const short*)&rt[(plocal + 1)*200 + cl]);
            o4.y = x4.y + sc*(xr + gv[1]*acc[1]);
            xr = bf2f(*(const short*)&rt[(plocal + 2)*200 + cl]);
            o4.z = x4.z + sc*(xr + gv[2]*acc[2]);
            xr = bf2f(*(const short*)&rt[(plocal + 3)*200 + cl]);
            o4.w = x4.w + sc*(xr + gv[3]*acc[3]);
            *(float4*)(ob + (size_t)c*HW + pbase) = o4;
        }
    }
}

extern "C" void kernel_launch(void* const* d_in, const int* in_sizes, int n_in,
                              void* d_out, int out_size, void* d_ws, size_t ws_size,
                              hipStream_t stream) {
    const float* x      = (const float*)d_in[0];
    const float* irf    = (const float*)d_in[1];
    const float* tf     = (const float*)d_in[2];
    const float* ln_g   = (const float*)d_in[3];
    const float* ln_b   = (const float*)d_in[4];
    const float* Wd     = (const float*)d_in[5];
    const float* bd     = (const float*)d_in[6];
    const float* Wu     = (const float*)d_in[7];
    const float* bu     = (const float*)d_in[8];
    const float* off_w  = (const float*)d_in[9];
    const float* off_b  = (const float*)d_in[10];
    const float* mod_w1 = (const float*)d_in[11];
    const float* mod_b1 = (const float*)d_in[12];
    const float* mod_w2 = (const float*)d_in[13];
    const float* mod_b2 = (const float*)d_in[14];
    const float* dc_w   = (const float*)d_in[15];
    const float* alpha  = (const float*)d_in[16];
    const float* Wk     = (const float*)d_in[17];
    const float* bk     = (const float*)d_in[18];
    const float* Wv     = (const float*)d_in[19];
    const float* bv     = (const float*)d_in[20];
    const float* temp   = (const float*)d_in[21];
    const float* Wg1    = (const float*)d_in[22];
    const float* bg1    = (const float*)d_in[23];
    const float* Wg2    = (const float*)d_in[24];
    const float* bg2    = (const float*)d_in[25];
    const float* scale  = (const float*)d_in[26];
    float* out = (float*)d_out;

    char* w = (char*)d_ws;
    auto alloc = [&](size_t bytes) {
        char* p = w;
        w += (bytes + 255) & ~(size_t)255;
        return p;
    };
    float* pk    = (float*)alloc((size_t)KP*C*4);
    float* pv    = (float*)alloc((size_t)KP*C*4);
    float* gbuf  = (float*)alloc((size_t)NPX*4);
    float* s12   = (float*)alloc((size_t)128*4);
    bf16* xres1  = (bf16*)alloc((size_t)NPX*C*2);
    bf16* pkn    = (bf16*)alloc((size_t)KP*C*2);
    bf16* pvt    = (bf16*)alloc((size_t)C*KP*2);
    bf16* atb    = (bf16*)alloc((size_t)NPX*KP*2);
    bf16* wg1f   = (bf16*)alloc((size_t)192*C*2);
    bf16* catb   = (bf16*)alloc((size_t)NPX*128*2);
    bf16* offwt  = (bf16*)alloc((size_t)32*1152*2);
    bf16* xfb    = (bf16*)alloc((size_t)NPX*BOT*2);
    bf16* wut    = (bf16*)alloc((size_t)C*BOT*2);
    bf16* mbf    = (bf16*)alloc((size_t)NPX*BOT*2);
    bf16* dcb2   = (bf16*)alloc((size_t)36864*2);
    bf16* wdt    = (bf16*)alloc((size_t)C*BOT*2);

    k_prep<<<193, 256, 0, stream>>>(Wd, ln_g, ln_b, bd, wdt, s12);
    k_stage1<<<2688, 256, 0, stream>>>(x, wdt, s12, catb,
                                       irf, mod_w1, mod_b1, mod_w2, mod_b2, mbf,
                                       off_w, dc_w, Wg1, Wu, tf, Wk, bk, Wv, bv,
                                       offwt, dcb2, wg1f, wut, pk, pv);
    k_offdef<<<512, 256, 0, stream>>>(catb, offwt, off_b, dcb2, mbf, alpha, xfb);
    k_stage2<<<2145, 256, 0, stream>>>(x, xfb, wut, bu, scale, xres1,
                                       pk, pv, pkn, pvt);
    k_attn_gate<<<1024, 256, 0, stream>>>(xres1, pkn, temp,
                                          wg1f, bg1, Wg2, bg2, atb, gbuf);
    k_out<<<dim3(512,4), 256, 0, stream>>>(x, xres1, atb, gbuf, pvt, scale, out);
}